// Round 15
// baseline (182.702 us; speedup 1.0000x reference)
//
#include <hip/hip_runtime.h>
#include <math.h>

// Problem constants (reference: N=200000, D=256, 2 heads, 2 att iters)
#define NROWS 200000
#define D 256
#define F4 64          // float4 per fp32 row

// colsum: 500 blocks x 400 rows (mixed R+W stream at its ceiling)
#define NBLK 500
#define CHUNK 400
#define CITERS 25
// bf16 passes: 1250 blocks x 160 rows -> ~5 blocks/CU, 20 waves/CU (TLP probe)
#define NBLK2 1250
#define CHUNK2 160
#define PITERS 10

// Workspace layout (floats). No atomics -> no zeroing.
// a1 stored as SIGN BYTES (a1 = sigmoid(+-1) exactly): 2*N bytes = 100000 float-slots.
#define WS_H1 0          // 512
#define WS_H2 512        // 512
#define WS_A  1024       // 100000 float-slots: 2*N sign bytes
#define WS_P  101024     // max(500*256, 1250*512) = 640000
#define WS_XB 741024     // bf16 copy of x: NROWS*512 bytes
// total = 741024*4 + 102,400,000 = 105,364,096 B (< 105,540,096 proven in r9)

__device__ __forceinline__ float att_sigmoid(float s) {
    float t = s / fmaxf(fabsf(s), 1e-12f);
    return 1.0f / (1.0f + __expf(-t));
}

// RNE float->bf16, pack two into one u32 (a = low short / even col)
__device__ __forceinline__ unsigned int packbf2(float a, float b) {
    unsigned int ua = __float_as_uint(a);
    unsigned int ub = __float_as_uint(b);
    ua = (ua + 0x7FFFu + ((ua >> 16) & 1u)) >> 16;
    ub = (ub + 0x7FFFu + ((ub >> 16) & 1u)) >> 16;
    return ua | (ub << 16);
}

__device__ __forceinline__ void unpack8(uint4 q, float* f) {
    f[0] = __uint_as_float(q.x << 16); f[1] = __uint_as_float(q.x & 0xFFFF0000u);
    f[2] = __uint_as_float(q.y << 16); f[3] = __uint_as_float(q.y & 0xFFFF0000u);
    f[4] = __uint_as_float(q.z << 16); f[5] = __uint_as_float(q.z & 0xFFFF0000u);
    f[6] = __uint_as_float(q.w << 16); f[7] = __uint_as_float(q.w & 0xFFFF0000u);
}

// ---- A: colsum partials + write bf16 copy of x ----
__global__ void __launch_bounds__(256) colsum_cast_kernel(const float* __restrict__ x,
                                                          float* __restrict__ part,
                                                          uint2* __restrict__ xb2) {
    const int tid = threadIdx.x, lane = tid & 63, wv = tid >> 6;
    const float4* x4 = reinterpret_cast<const float4*>(x);
    const int r0 = blockIdx.x * CHUNK + wv * 4;
    const size_t base = (size_t)r0 * F4 + lane;
    float4 cur[4], nxt[4];
#pragma unroll
    for (int j = 0; j < 4; ++j) cur[j] = x4[base + j * F4];
    float4 accA = make_float4(0.f, 0.f, 0.f, 0.f);
    float4 accB = make_float4(0.f, 0.f, 0.f, 0.f);
    for (int it = 0; it < CITERS; ++it) {
        if (it + 1 < CITERS) {
            size_t nb = base + (size_t)(it + 1) * 16 * F4;
#pragma unroll
            for (int j = 0; j < 4; ++j) nxt[j] = x4[nb + j * F4];
        }
        accA.x += cur[0].x + cur[1].x; accB.x += cur[2].x + cur[3].x;
        accA.y += cur[0].y + cur[1].y; accB.y += cur[2].y + cur[3].y;
        accA.z += cur[0].z + cur[1].z; accB.z += cur[2].z + cur[3].z;
        accA.w += cur[0].w + cur[1].w; accB.w += cur[2].w + cur[3].w;
        const int rb = r0 + it * 16;
#pragma unroll
        for (int j = 0; j < 4; ++j) {
            xb2[(size_t)(rb + j) * 64 + lane] =
                make_uint2(packbf2(cur[j].x, cur[j].y), packbf2(cur[j].z, cur[j].w));
        }
        if (it + 1 < CITERS) {
#pragma unroll
            for (int j = 0; j < 4; ++j) cur[j] = nxt[j];
        }
    }
    accA.x += accB.x; accA.y += accB.y; accA.z += accB.z; accA.w += accB.w;
    __shared__ float4 sh[256];
    sh[tid] = accA;
    __syncthreads();
    if (tid < 64) {
        float4 a = sh[tid], b = sh[tid + 64], c = sh[tid + 128], d = sh[tid + 192];
        float4 s;
        s.x = (a.x + b.x) + (c.x + d.x);
        s.y = (a.y + b.y) + (c.y + d.y);
        s.z = (a.z + b.z) + (c.z + d.z);
        s.w = (a.w + b.w) + (c.w + d.w);
        reinterpret_cast<float4*>(part)[blockIdx.x * 64 + tid] = s;
    }
}

// ---- fused: reduce nparts partial rows -> v, then h = tanh((v*scale) @ W) ----
__global__ void __launch_bounds__(256) hproj_fused(const float* __restrict__ W,
                                                   const float* __restrict__ part,
                                                   int width4, int headOff4, int nparts,
                                                   float scale, float* __restrict__ hout) {
    const int head = blockIdx.x;
    const int tid = threadIdx.x, lane = tid & 63, wv = tid >> 6;
    const float4* p4 = reinterpret_cast<const float4*>(part) + head * headOff4 + lane;
    float4 s = make_float4(0.f, 0.f, 0.f, 0.f);
#pragma unroll 5
    for (int r = wv; r < nparts; r += 4) {
        float4 v = p4[(size_t)r * width4];
        s.x += v.x; s.y += v.y; s.z += v.z; s.w += v.w;
    }
    __shared__ float4 red[4][64];
    __shared__ float vbuf[D];
    red[wv][lane] = s;
    __syncthreads();
    if (tid < 64) {
        float4 a = red[0][tid], b = red[1][tid], c = red[2][tid], d = red[3][tid];
        vbuf[tid * 4 + 0] = ((a.x + b.x) + (c.x + d.x)) * scale;
        vbuf[tid * 4 + 1] = ((a.y + b.y) + (c.y + d.y)) * scale;
        vbuf[tid * 4 + 2] = ((a.z + b.z) + (c.z + d.z)) * scale;
        vbuf[tid * 4 + 3] = ((a.w + b.w) + (c.w + d.w)) * scale;
    }
    __syncthreads();
    const float* Wh = W + head * D * D;
    float acc = 0.0f;
#pragma unroll 8
    for (int k = 0; k < D; ++k) acc = fmaf(vbuf[k], Wh[k * D + tid], acc);
    hout[head * D + tid] = tanhf(acc);
}

// ---- C: pass1 on bf16 copy (1250 blocks); store a1 sign bytes ----
// Wave covers 4 rows/iter. Lane: hi=lane>>5 row parity, chunk=lane&31 -> cols chunk*8..+7.
__global__ void __launch_bounds__(256) pass1_bf16_kernel(const uint4* __restrict__ xb,
                                                         float* __restrict__ ws) {
    const float* h = ws + WS_H1;
    unsigned char* aB0 = reinterpret_cast<unsigned char*>(ws + WS_A);
    unsigned char* aB1 = aB0 + NROWS;
    float* part = ws + WS_P;
    const int tid = threadIdx.x, lane = tid & 63, wv = tid >> 6;
    const int hi = lane >> 5, chunk = lane & 31, c0 = chunk * 8;
    const int r0 = blockIdx.x * CHUNK2 + wv * 4;
    float hh0[8], hh1[8];
#pragma unroll
    for (int k = 0; k < 8; ++k) { hh0[k] = h[c0 + k]; hh1[k] = h[D + c0 + k]; }
    float acc0[8], acc1[8];
#pragma unroll
    for (int k = 0; k < 8; ++k) { acc0[k] = 0.f; acc1[k] = 0.f; }
    const size_t base = (size_t)r0 * 32;   // 32 uint4 per row
    uint4 cur0 = xb[base + lane];
    uint4 cur1 = xb[base + 64 + lane];
    for (int it = 0; it < PITERS; ++it) {
        uint4 nxt0, nxt1;
        if (it + 1 < PITERS) {
            const size_t nb = base + (size_t)(it + 1) * 512;
            nxt0 = xb[nb + lane];
            nxt1 = xb[nb + 64 + lane];
        }
        float f0[8], f1[8];
        unpack8(cur0, f0);
        unpack8(cur1, f1);
        float d00 = 0.f, d01 = 0.f, d10 = 0.f, d11 = 0.f;  // d{head}{rowpair}
#pragma unroll
        for (int k = 0; k < 8; ++k) {
            d00 = fmaf(f0[k], hh0[k], d00); d10 = fmaf(f0[k], hh1[k], d10);
            d01 = fmaf(f1[k], hh0[k], d01); d11 = fmaf(f1[k], hh1[k], d11);
        }
#pragma unroll
        for (int off = 1; off < 32; off <<= 1) {
            d00 += __shfl_xor(d00, off); d01 += __shfl_xor(d01, off);
            d10 += __shfl_xor(d10, off); d11 += __shfl_xor(d11, off);
        }
        float a00 = att_sigmoid(d00), a01 = att_sigmoid(d01);
        float a10 = att_sigmoid(d10), a11 = att_sigmoid(d11);
        const int rb = r0 + it * 16;
        if (chunk == 0) {
            aB0[rb + hi] = (d00 >= 0.f);
            aB0[rb + 2 + hi] = (d01 >= 0.f);
            aB1[rb + hi] = (d10 >= 0.f);
            aB1[rb + 2 + hi] = (d11 >= 0.f);
        }
#pragma unroll
        for (int k = 0; k < 8; ++k) {
            acc0[k] = fmaf(a00, f0[k], acc0[k]); acc0[k] = fmaf(a01, f1[k], acc0[k]);
            acc1[k] = fmaf(a10, f0[k], acc1[k]); acc1[k] = fmaf(a11, f1[k], acc1[k]);
        }
        cur0 = nxt0; cur1 = nxt1;
    }
    __shared__ float lds[256][17];
#pragma unroll
    for (int k = 0; k < 8; ++k) { lds[tid][k] = acc0[k]; lds[tid][8 + k] = acc1[k]; }
    __syncthreads();
    float s0 = 0.f, s1 = 0.f;
#pragma unroll
    for (int g = 0; g < 8; ++g) {
        s0 += lds[g * 32 + (tid >> 3)][tid & 7];
        s1 += lds[g * 32 + (tid >> 3)][8 + (tid & 7)];
    }
    part[blockIdx.x * 512 + tid] = s0;
    part[blockIdx.x * 512 + 256 + tid] = s1;
}

// ---- E: pass2 on bf16 copy (1250 blocks); a1 from sign bytes ----
__global__ void __launch_bounds__(256) pass2_bf16_kernel(const uint4* __restrict__ xb,
                                                         float* __restrict__ ws) {
    const float* h = ws + WS_H2;
    const unsigned char* aB0 = reinterpret_cast<const unsigned char*>(ws + WS_A);
    const unsigned char* aB1 = aB0 + NROWS;
    float* part = ws + WS_P;
    const int tid = threadIdx.x, lane = tid & 63, wv = tid >> 6;
    const int hi = lane >> 5, chunk = lane & 31, c0 = chunk * 8;
    const int r0 = blockIdx.x * CHUNK2 + wv * 4;
    // a1 = att_sigmoid(+-1) exactly (t = s/|s| = +-1 in fp32) -> rebuild from sign
    const float SIG[2] = {att_sigmoid(-1.0f), att_sigmoid(1.0f)};
    float hh0[8], hh1[8];
#pragma unroll
    for (int k = 0; k < 8; ++k) { hh0[k] = h[c0 + k]; hh1[k] = h[D + c0 + k]; }
    float acc0[8], acc1[8];
#pragma unroll
    for (int k = 0; k < 8; ++k) { acc0[k] = 0.f; acc1[k] = 0.f; }
    const size_t base = (size_t)r0 * 32;
    uint4 cur0 = xb[base + lane];
    uint4 cur1 = xb[base + 64 + lane];
    for (int it = 0; it < PITERS; ++it) {
        uint4 nxt0, nxt1;
        if (it + 1 < PITERS) {
            const size_t nb = base + (size_t)(it + 1) * 512;
            nxt0 = xb[nb + lane];
            nxt1 = xb[nb + 64 + lane];
        }
        const int rb = r0 + it * 16;
        float aa00 = SIG[aB0[rb + hi]], aa01 = SIG[aB0[rb + 2 + hi]];
        float aa10 = SIG[aB1[rb + hi]], aa11 = SIG[aB1[rb + 2 + hi]];
        float f0[8], f1[8];
        unpack8(cur0, f0);
        unpack8(cur1, f1);
        float d00 = 0.f, d01 = 0.f, d10 = 0.f, d11 = 0.f;
#pragma unroll
        for (int k = 0; k < 8; ++k) {
            d00 = fmaf(f0[k], hh0[k], d00); d10 = fmaf(f0[k], hh1[k], d10);
            d01 = fmaf(f1[k], hh0[k], d01); d11 = fmaf(f1[k], hh1[k], d11);
        }
#pragma unroll
        for (int off = 1; off < 32; off <<= 1) {
            d00 += __shfl_xor(d00, off); d01 += __shfl_xor(d01, off);
            d10 += __shfl_xor(d10, off); d11 += __shfl_xor(d11, off);
        }
        float w00 = att_sigmoid(aa00 * d00) * aa00;
        float w01 = att_sigmoid(aa01 * d01) * aa01;
        float w10 = att_sigmoid(aa10 * d10) * aa10;
        float w11 = att_sigmoid(aa11 * d11) * aa11;
#pragma unroll
        for (int k = 0; k < 8; ++k) {
            acc0[k] = fmaf(w00, f0[k], acc0[k]); acc0[k] = fmaf(w01, f1[k], acc0[k]);
            acc1[k] = fmaf(w10, f0[k], acc1[k]); acc1[k] = fmaf(w11, f1[k], acc1[k]);
        }
        cur0 = nxt0; cur1 = nxt1;
    }
    __shared__ float lds[256][17];
#pragma unroll
    for (int k = 0; k < 8; ++k) { lds[tid][k] = acc0[k]; lds[tid][8 + k] = acc1[k]; }
    __syncthreads();
    float s0 = 0.f, s1 = 0.f;
#pragma unroll
    for (int g = 0; g < 8; ++g) {
        s0 += lds[g * 32 + (tid >> 3)][tid & 7];
        s1 += lds[g * 32 + (tid >> 3)][8 + (tid & 7)];
    }
    part[blockIdx.x * 512 + tid] = s0;
    part[blockIdx.x * 512 + 256 + tid] = s1;
}

// ---- final: out[head*256+c] = sum over NBLK2 partial rows (direct store) ----
__global__ void __launch_bounds__(256) out_reduce(const float* __restrict__ part,
                                                  float* __restrict__ out) {
    const int head = blockIdx.x;
    const int tid = threadIdx.x, lane = tid & 63, wv = tid >> 6;
    const float4* p4 = reinterpret_cast<const float4*>(part) + head * 64 + lane;
    float4 s = make_float4(0.f, 0.f, 0.f, 0.f);
#pragma unroll 5
    for (int r = wv; r < NBLK2; r += 4) {
        float4 v = p4[(size_t)r * 128];
        s.x += v.x; s.y += v.y; s.z += v.z; s.w += v.w;
    }
    __shared__ float4 red[4][64];
    red[wv][lane] = s;
    __syncthreads();
    if (tid < 64) {
        float4 a = red[0][tid], b = red[1][tid], c = red[2][tid], d = red[3][tid];
        float4 o;
        o.x = (a.x + b.x) + (c.x + d.x);
        o.y = (a.y + b.y) + (c.y + d.y);
        o.z = (a.z + b.z) + (c.z + d.z);
        o.w = (a.w + b.w) + (c.w + d.w);
        reinterpret_cast<float4*>(out)[head * 64 + tid] = o;
    }
}

extern "C" void kernel_launch(void* const* d_in, const int* in_sizes, int n_in,
                              void* d_out, int out_size, void* d_ws, size_t ws_size,
                              hipStream_t stream) {
    const float* x = (const float*)d_in[0];   // (200000, 256) f32
    const float* W = (const float*)d_in[1];   // (2, 256, 256) f32
    float* out = (float*)d_out;               // (1, 512) f32
    float* ws = (float*)d_ws;

    uint2* xb2 = reinterpret_cast<uint2*>(ws + WS_XB);
    const uint4* xb4 = reinterpret_cast<const uint4*>(ws + WS_XB);

    colsum_cast_kernel<<<dim3(NBLK), dim3(256), 0, stream>>>(x, ws + WS_P, xb2);
    hproj_fused<<<dim3(2), dim3(256), 0, stream>>>(W, ws + WS_P, 64, 0, NBLK,
                                                   1.0f / NROWS, ws + WS_H1);
    pass1_bf16_kernel<<<dim3(NBLK2), dim3(256), 0, stream>>>(xb4, ws);
    hproj_fused<<<dim3(2), dim3(256), 0, stream>>>(W, ws + WS_P, 128, 64, NBLK2,
                                                   1.0f / NROWS, ws + WS_H2);
    pass2_bf16_kernel<<<dim3(NBLK2), dim3(256), 0, stream>>>(xb4, ws);
    out_reduce<<<dim3(2), dim3(256), 0, stream>>>(ws + WS_P, out);
}

// Round 16
// 157.933 us; speedup vs baseline: 1.1568x; 1.1568x over previous
//
#include <hip/hip_runtime.h>
#include <math.h>

// Problem constants (reference: N=200000, D=256, 2 heads, 2 att iters)
#define NROWS 200000
#define D 256
#define F4 64          // float4 per row

// Grid: 500 blocks x 400 rows = 200000 exactly. Block = 4 waves;
// wave = 4 consecutive rows per iter, 25 iters, depth-1 prefetch.
// MEASURED (r2/r5/r7/r12/r15): more blocks, deeper prefetch, wider batches all
// REGRESS — these streamers are pinned at ~4.6-5.1 TB/s effective on MI355X.
// MEASURED (r8/r11): grid.sync / __threadfence after large dirty writes cost
// ~100 us-class — kernel boundaries are the cheapest global sync.
#define NBLK 500
#define CHUNK 400
#define ITERS 25

// Workspace layout (floats). No atomics -> no zeroing.
#define WS_H1 0          // 512   per-head h1
#define WS_H2 512        // 512   per-head h2
#define WS_A  1024       // 2*N   a1 per row (head0 then head1)
#define WS_P1 401024     // 500*256 colsum partials
#define WS_P2 529024     // 500*512 pass partials
#define WS_XB 785024     // bf16 copy of x: NROWS*512 bytes

__device__ __forceinline__ float att_sigmoid(float s) {
    float t = s / fmaxf(fabsf(s), 1e-12f);
    return 1.0f / (1.0f + __expf(-t));
}

// RNE float->bf16, pack two into one u32 (a = low short / even col)
__device__ __forceinline__ unsigned int packbf2(float a, float b) {
    unsigned int ua = __float_as_uint(a);
    unsigned int ub = __float_as_uint(b);
    ua = (ua + 0x7FFFu + ((ua >> 16) & 1u)) >> 16;
    ub = (ub + 0x7FFFu + ((ub >> 16) & 1u)) >> 16;
    return ua | (ub << 16);
}

__device__ __forceinline__ void unpack8(uint4 q, float* f) {
    f[0] = __uint_as_float(q.x << 16); f[1] = __uint_as_float(q.x & 0xFFFF0000u);
    f[2] = __uint_as_float(q.y << 16); f[3] = __uint_as_float(q.y & 0xFFFF0000u);
    f[4] = __uint_as_float(q.z << 16); f[5] = __uint_as_float(q.z & 0xFFFF0000u);
    f[6] = __uint_as_float(q.w << 16); f[7] = __uint_as_float(q.w & 0xFFFF0000u);
}

// ---- A: colsum partials + write bf16 copy of x ----
__global__ void __launch_bounds__(256) colsum_cast_kernel(const float* __restrict__ x,
                                                          float* __restrict__ part,
                                                          uint2* __restrict__ xb2) {
    const int tid = threadIdx.x, lane = tid & 63, wv = tid >> 6;
    const float4* x4 = reinterpret_cast<const float4*>(x);
    const int r0 = blockIdx.x * CHUNK + wv * 4;
    const size_t base = (size_t)r0 * F4 + lane;
    float4 cur[4], nxt[4];
#pragma unroll
    for (int j = 0; j < 4; ++j) cur[j] = x4[base + j * F4];
    float4 accA = make_float4(0.f, 0.f, 0.f, 0.f);
    float4 accB = make_float4(0.f, 0.f, 0.f, 0.f);
    for (int it = 0; it < ITERS; ++it) {
        if (it + 1 < ITERS) {
            size_t nb = base + (size_t)(it + 1) * 16 * F4;
#pragma unroll
            for (int j = 0; j < 4; ++j) nxt[j] = x4[nb + j * F4];
        }
        accA.x += cur[0].x + cur[1].x; accB.x += cur[2].x + cur[3].x;
        accA.y += cur[0].y + cur[1].y; accB.y += cur[2].y + cur[3].y;
        accA.z += cur[0].z + cur[1].z; accB.z += cur[2].z + cur[3].z;
        accA.w += cur[0].w + cur[1].w; accB.w += cur[2].w + cur[3].w;
        const int rb = r0 + it * 16;
#pragma unroll
        for (int j = 0; j < 4; ++j) {
            xb2[(size_t)(rb + j) * 64 + lane] =
                make_uint2(packbf2(cur[j].x, cur[j].y), packbf2(cur[j].z, cur[j].w));
        }
        if (it + 1 < ITERS) {
#pragma unroll
            for (int j = 0; j < 4; ++j) cur[j] = nxt[j];
        }
    }
    accA.x += accB.x; accA.y += accB.y; accA.z += accB.z; accA.w += accB.w;
    __shared__ float4 sh[256];
    sh[tid] = accA;
    __syncthreads();
    if (tid < 64) {
        float4 a = sh[tid], b = sh[tid + 64], c = sh[tid + 128], d = sh[tid + 192];
        float4 s;
        s.x = (a.x + b.x) + (c.x + d.x);
        s.y = (a.y + b.y) + (c.y + d.y);
        s.z = (a.z + b.z) + (c.z + d.z);
        s.w = (a.w + b.w) + (c.w + d.w);
        reinterpret_cast<float4*>(part)[blockIdx.x * 64 + tid] = s;
    }
}

// ---- fused: reduce NBLK partial rows -> v, then h = tanh((v*scale) @ W) ----
__global__ void __launch_bounds__(256) hproj_fused(const float* __restrict__ W,
                                                   const float* __restrict__ part,
                                                   int width4, int headOff4, float scale,
                                                   float* __restrict__ hout) {
    const int head = blockIdx.x;
    const int tid = threadIdx.x, lane = tid & 63, wv = tid >> 6;
    const float4* p4 = reinterpret_cast<const float4*>(part) + head * headOff4 + lane;
    float4 s = make_float4(0.f, 0.f, 0.f, 0.f);
#pragma unroll 5
    for (int r = wv; r < NBLK; r += 4) {
        float4 v = p4[(size_t)r * width4];
        s.x += v.x; s.y += v.y; s.z += v.z; s.w += v.w;
    }
    __shared__ float4 red[4][64];
    __shared__ float vbuf[D];
    red[wv][lane] = s;
    __syncthreads();
    if (tid < 64) {
        float4 a = red[0][tid], b = red[1][tid], c = red[2][tid], d = red[3][tid];
        vbuf[tid * 4 + 0] = ((a.x + b.x) + (c.x + d.x)) * scale;
        vbuf[tid * 4 + 1] = ((a.y + b.y) + (c.y + d.y)) * scale;
        vbuf[tid * 4 + 2] = ((a.z + b.z) + (c.z + d.z)) * scale;
        vbuf[tid * 4 + 3] = ((a.w + b.w) + (c.w + d.w)) * scale;
    }
    __syncthreads();
    const float* Wh = W + head * D * D;
    float acc = 0.0f;
#pragma unroll 8
    for (int k = 0; k < D; ++k) acc = fmaf(vbuf[k], Wh[k * D + tid], acc);
    hout[head * D + tid] = tanhf(acc);
}

// ---- C: pass1 on bf16 copy ----
// Wave covers 4 rows/iter. Lane: hi=lane>>5 row parity, chunk=lane&31 -> cols chunk*8..+7.
__global__ void __launch_bounds__(256) pass1_bf16_kernel(const uint4* __restrict__ xb,
                                                         float* __restrict__ ws) {
    const float* h = ws + WS_H1;
    float* aA0 = ws + WS_A;
    float* aA1 = ws + WS_A + NROWS;
    float* part = ws + WS_P2;
    const int tid = threadIdx.x, lane = tid & 63, wv = tid >> 6;
    const int hi = lane >> 5, chunk = lane & 31, c0 = chunk * 8;
    const int r0 = blockIdx.x * CHUNK + wv * 4;
    float hh0[8], hh1[8];
#pragma unroll
    for (int k = 0; k < 8; ++k) { hh0[k] = h[c0 + k]; hh1[k] = h[D + c0 + k]; }
    float acc0[8], acc1[8];
#pragma unroll
    for (int k = 0; k < 8; ++k) { acc0[k] = 0.f; acc1[k] = 0.f; }
    const size_t base = (size_t)r0 * 32;   // 32 uint4 per row
    uint4 cur0 = xb[base + lane];
    uint4 cur1 = xb[base + 64 + lane];
    for (int it = 0; it < ITERS; ++it) {
        uint4 nxt0, nxt1;
        if (it + 1 < ITERS) {
            const size_t nb = base + (size_t)(it + 1) * 512;
            nxt0 = xb[nb + lane];
            nxt1 = xb[nb + 64 + lane];
        }
        float f0[8], f1[8];
        unpack8(cur0, f0);
        unpack8(cur1, f1);
        float d00 = 0.f, d01 = 0.f, d10 = 0.f, d11 = 0.f;  // d{head}{rowpair}
#pragma unroll
        for (int k = 0; k < 8; ++k) {
            d00 = fmaf(f0[k], hh0[k], d00); d10 = fmaf(f0[k], hh1[k], d10);
            d01 = fmaf(f1[k], hh0[k], d01); d11 = fmaf(f1[k], hh1[k], d11);
        }
#pragma unroll
        for (int off = 1; off < 32; off <<= 1) {
            d00 += __shfl_xor(d00, off); d01 += __shfl_xor(d01, off);
            d10 += __shfl_xor(d10, off); d11 += __shfl_xor(d11, off);
        }
        float a00 = att_sigmoid(d00), a01 = att_sigmoid(d01);
        float a10 = att_sigmoid(d10), a11 = att_sigmoid(d11);
        const int rb = r0 + it * 16;
        if (chunk == 0) {
            aA0[rb + hi] = a00; aA0[rb + 2 + hi] = a01;
            aA1[rb + hi] = a10; aA1[rb + 2 + hi] = a11;
        }
#pragma unroll
        for (int k = 0; k < 8; ++k) {
            acc0[k] = fmaf(a00, f0[k], acc0[k]); acc0[k] = fmaf(a01, f1[k], acc0[k]);
            acc1[k] = fmaf(a10, f0[k], acc1[k]); acc1[k] = fmaf(a11, f1[k], acc1[k]);
        }
        cur0 = nxt0; cur1 = nxt1;
    }
    __shared__ float lds[256][17];
#pragma unroll
    for (int k = 0; k < 8; ++k) { lds[tid][k] = acc0[k]; lds[tid][8 + k] = acc1[k]; }
    __syncthreads();
    float s0 = 0.f, s1 = 0.f;
#pragma unroll
    for (int g = 0; g < 8; ++g) {
        s0 += lds[g * 32 + (tid >> 3)][tid & 7];
        s1 += lds[g * 32 + (tid >> 3)][8 + (tid & 7)];
    }
    part[blockIdx.x * 512 + tid] = s0;
    part[blockIdx.x * 512 + 256 + tid] = s1;
}

// ---- E: pass2 on bf16 copy ----
__global__ void __launch_bounds__(256) pass2_bf16_kernel(const uint4* __restrict__ xb,
                                                         float* __restrict__ ws) {
    const float* h = ws + WS_H2;
    const float* aA0 = ws + WS_A;
    const float* aA1 = ws + WS_A + NROWS;
    float* part = ws + WS_P2;
    const int tid = threadIdx.x, lane = tid & 63, wv = tid >> 6;
    const int hi = lane >> 5, chunk = lane & 31, c0 = chunk * 8;
    const int r0 = blockIdx.x * CHUNK + wv * 4;
    float hh0[8], hh1[8];
#pragma unroll
    for (int k = 0; k < 8; ++k) { hh0[k] = h[c0 + k]; hh1[k] = h[D + c0 + k]; }
    float acc0[8], acc1[8];
#pragma unroll
    for (int k = 0; k < 8; ++k) { acc0[k] = 0.f; acc1[k] = 0.f; }
    const size_t base = (size_t)r0 * 32;
    uint4 cur0 = xb[base + lane];
    uint4 cur1 = xb[base + 64 + lane];
    for (int it = 0; it < ITERS; ++it) {
        uint4 nxt0, nxt1;
        if (it + 1 < ITERS) {
            const size_t nb = base + (size_t)(it + 1) * 512;
            nxt0 = xb[nb + lane];
            nxt1 = xb[nb + 64 + lane];
        }
        const int rb = r0 + it * 16;
        float aa00 = aA0[rb + hi], aa01 = aA0[rb + 2 + hi];
        float aa10 = aA1[rb + hi], aa11 = aA1[rb + 2 + hi];
        float f0[8], f1[8];
        unpack8(cur0, f0);
        unpack8(cur1, f1);
        float d00 = 0.f, d01 = 0.f, d10 = 0.f, d11 = 0.f;
#pragma unroll
        for (int k = 0; k < 8; ++k) {
            d00 = fmaf(f0[k], hh0[k], d00); d10 = fmaf(f0[k], hh1[k], d10);
            d01 = fmaf(f1[k], hh0[k], d01); d11 = fmaf(f1[k], hh1[k], d11);
        }
#pragma unroll
        for (int off = 1; off < 32; off <<= 1) {
            d00 += __shfl_xor(d00, off); d01 += __shfl_xor(d01, off);
            d10 += __shfl_xor(d10, off); d11 += __shfl_xor(d11, off);
        }
        float w00 = att_sigmoid(aa00 * d00) * aa00;
        float w01 = att_sigmoid(aa01 * d01) * aa01;
        float w10 = att_sigmoid(aa10 * d10) * aa10;
        float w11 = att_sigmoid(aa11 * d11) * aa11;
#pragma unroll
        for (int k = 0; k < 8; ++k) {
            acc0[k] = fmaf(w00, f0[k], acc0[k]); acc0[k] = fmaf(w01, f1[k], acc0[k]);
            acc1[k] = fmaf(w10, f0[k], acc1[k]); acc1[k] = fmaf(w11, f1[k], acc1[k]);
        }
        cur0 = nxt0; cur1 = nxt1;
    }
    __shared__ float lds[256][17];
#pragma unroll
    for (int k = 0; k < 8; ++k) { lds[tid][k] = acc0[k]; lds[tid][8 + k] = acc1[k]; }
    __syncthreads();
    float s0 = 0.f, s1 = 0.f;
#pragma unroll
    for (int g = 0; g < 8; ++g) {
        s0 += lds[g * 32 + (tid >> 3)][tid & 7];
        s1 += lds[g * 32 + (tid >> 3)][8 + (tid & 7)];
    }
    part[blockIdx.x * 512 + tid] = s0;
    part[blockIdx.x * 512 + 256 + tid] = s1;
}

// ---- final: out[head*256+c] = sum over NBLK partial rows (direct store) ----
__global__ void __launch_bounds__(256) out_reduce(const float* __restrict__ part,
                                                  float* __restrict__ out) {
    const int head = blockIdx.x;
    const int tid = threadIdx.x, lane = tid & 63, wv = tid >> 6;
    const float4* p4 = reinterpret_cast<const float4*>(part) + head * 64 + lane;
    float4 s = make_float4(0.f, 0.f, 0.f, 0.f);
#pragma unroll 5
    for (int r = wv; r < NBLK; r += 4) {
        float4 v = p4[(size_t)r * 128];
        s.x += v.x; s.y += v.y; s.z += v.z; s.w += v.w;
    }
    __shared__ float4 red[4][64];
    red[wv][lane] = s;
    __syncthreads();
    if (tid < 64) {
        float4 a = red[0][tid], b = red[1][tid], c = red[2][tid], d = red[3][tid];
        float4 o;
        o.x = (a.x + b.x) + (c.x + d.x);
        o.y = (a.y + b.y) + (c.y + d.y);
        o.z = (a.z + b.z) + (c.z + d.z);
        o.w = (a.w + b.w) + (c.w + d.w);
        reinterpret_cast<float4*>(out)[head * 64 + tid] = o;
    }
}

extern "C" void kernel_launch(void* const* d_in, const int* in_sizes, int n_in,
                              void* d_out, int out_size, void* d_ws, size_t ws_size,
                              hipStream_t stream) {
    const float* x = (const float*)d_in[0];   // (200000, 256) f32
    const float* W = (const float*)d_in[1];   // (2, 256, 256) f32
    float* out = (float*)d_out;               // (1, 512) f32
    float* ws = (float*)d_ws;

    uint2* xb2 = reinterpret_cast<uint2*>(ws + WS_XB);
    const uint4* xb4 = reinterpret_cast<const uint4*>(ws + WS_XB);

    colsum_cast_kernel<<<dim3(NBLK), dim3(256), 0, stream>>>(x, ws + WS_P1, xb2);
    hproj_fused<<<dim3(2), dim3(256), 0, stream>>>(W, ws + WS_P1, 64, 0, 1.0f / NROWS, ws + WS_H1);
    pass1_bf16_kernel<<<dim3(NBLK), dim3(256), 0, stream>>>(xb4, ws);
    hproj_fused<<<dim3(2), dim3(256), 0, stream>>>(W, ws + WS_P2, 128, 64, 1.0f / NROWS, ws + WS_H2);
    pass2_bf16_kernel<<<dim3(NBLK), dim3(256), 0, stream>>>(xb4, ws);
    out_reduce<<<dim3(2), dim3(256), 0, stream>>>(ws + WS_P2, out);
}